// Round 2
// baseline (451.877 us; speedup 1.0000x reference)
//
#include <hip/hip_runtime.h>
#include <cstdint>
#include <cstddef>

#define NNODES 20000
#define NEDGES 160000
#define DFEAT  128
#define NEXP   4

// ---------------- workspace layout (float-element offsets) ----------------
// 0        deg_f       [20000]  (zeroed)
// 20000    cursor(int) [20000]  (zeroed)
// 40000    importance  [8]      (zeroed)
// 40960    rowstart(int)[20001]
// 61440    csr_src(int)[160000]
// 221440   csr_nrm     [160000]
// 381440   gates       [80000]
// 461440   agg_x       [2560000]
// 3021440  h           [10240000]
// 13261440 agg_h       [10240000]
// total 23501440 floats = ~94 MB

// ---------------------------------------------------------------- degree
__global__ void k_deg(const int* __restrict__ ei, float* __restrict__ deg) {
    int e = blockIdx.x * 256 + threadIdx.x;
    if (e < NEDGES) atomicAdd(&deg[ei[NEDGES + e]], 1.0f);
}

// ------------------------------------------------- exclusive scan (1 block)
__global__ void k_scan(const float* __restrict__ deg, int* __restrict__ rowstart) {
    __shared__ int part[256];
    int t = threadIdx.x;
    const int PER = (NNODES + 255) / 256;  // 79
    int base = t * PER;
    int s = 0;
    for (int i = 0; i < PER; ++i) {
        int n = base + i;
        if (n < NNODES) s += (int)deg[n];
    }
    part[t] = s;
    __syncthreads();
    for (int off = 1; off < 256; off <<= 1) {
        int v = (t >= off) ? part[t - off] : 0;
        __syncthreads();
        part[t] += v;
        __syncthreads();
    }
    int run = part[t] - s;  // exclusive prefix for this chunk
    for (int i = 0; i < PER; ++i) {
        int n = base + i;
        if (n < NNODES) {
            rowstart[n] = run;
            run += (int)deg[n];
        }
    }
    if (t == 255) rowstart[NNODES] = part[255];
}

// ------------------------------------------------------- CSR fill + norm
__global__ void k_fill(const int* __restrict__ ei, const float* __restrict__ deg,
                       const int* __restrict__ rowstart, int* __restrict__ cursor,
                       int* __restrict__ csrc, float* __restrict__ cnrm) {
    int e = blockIdx.x * 256 + threadIdx.x;
    if (e >= NEDGES) return;
    int s = ei[e], d = ei[NEDGES + e];
    int pos = atomicAdd(&cursor[d], 1);
    int slot = rowstart[d] + pos;
    csrc[slot] = s;
    float ds = fmaxf(deg[s], 1.0f), dd = fmaxf(deg[d], 1.0f);
    cnrm[slot] = 1.0f / sqrtf(ds * dd);
}

// ------------------------------------------------------------- gating
__global__ void k_gate(const float* __restrict__ x_agg, const float* __restrict__ w_gate,
                       const float* __restrict__ thr, const float* __restrict__ mask,
                       float* __restrict__ gates, float* __restrict__ importance) {
    int n = blockIdx.x * 256 + threadIdx.x;
    float4 lg = make_float4(0.f, 0.f, 0.f, 0.f);
    if (n < NNODES) {
        const float4* xr = (const float4*)(x_agg + (size_t)n * DFEAT);
        const float4* wg = (const float4*)w_gate;  // [128 rows][4] -> one float4 per row
        for (int k4 = 0; k4 < 32; ++k4) {
            float4 xv = xr[k4];
            float4 w0 = wg[4 * k4 + 0], w1 = wg[4 * k4 + 1];
            float4 w2 = wg[4 * k4 + 2], w3 = wg[4 * k4 + 3];
            lg.x += xv.x * w0.x + xv.y * w1.x + xv.z * w2.x + xv.w * w3.x;
            lg.y += xv.x * w0.y + xv.y * w1.y + xv.z * w2.y + xv.w * w3.y;
            lg.z += xv.x * w0.z + xv.y * w1.z + xv.z * w2.z + xv.w * w3.z;
            lg.w += xv.x * w0.w + xv.y * w1.w + xv.z * w2.w + xv.w * w3.w;
        }
    }
    float g[4];
    float lv[4] = {lg.x, lg.y, lg.z, lg.w};
    for (int e = 0; e < 4; ++e) {
        float sgm = 1.0f / (1.0f + expf(-lv[e]));
        float sdiff = sgm - thr[e];
        g[e] = (sdiff > 0.0f) ? mask[e] : 0.0f;
        if (n >= NNODES) g[e] = 0.0f;  // keep reduction clean on tail lanes
    }
    if (n < NNODES) {
        ((float4*)gates)[n] = make_float4(g[0], g[1], g[2], g[3]);
    }
    // wave-level reduce then one atomic per wave per expert
    int lane = threadIdx.x & 63;
    for (int e = 0; e < 4; ++e) {
        float v = g[e];
        for (int off = 32; off >= 1; off >>= 1) v += __shfl_down(v, off);
        if (lane == 0) atomicAdd(&importance[e], v);
    }
}

// ------------------------------------------------ normalized neighbor sum
// one half-wave group of 32 threads handles (expert,node); each thread 4 feats
__global__ void k_gatheragg(const float* __restrict__ feat, const int* __restrict__ rowstart,
                            const int* __restrict__ csrc, const float* __restrict__ cnrm,
                            float* __restrict__ out, int nexp) {
    int gid = blockIdx.x * 256 + threadIdx.x;
    int total = nexp * NNODES * 32;
    if (gid >= total) return;
    int c4 = gid & 31;
    int ni = gid >> 5;
    int node = ni % NNODES;
    int e = ni / NNODES;
    const float* fb = feat + (size_t)e * NNODES * DFEAT;
    int r0 = rowstart[node], r1 = rowstart[node + 1];
    float ax = 0.f, ay = 0.f, az = 0.f, aw = 0.f;
    for (int j = r0; j < r1; ++j) {
        int s = csrc[j];
        float w = cnrm[j];
        float4 v = *(const float4*)(fb + (size_t)s * DFEAT + c4 * 4);
        ax += w * v.x; ay += w * v.y; az += w * v.z; aw += w * v.w;
    }
    ((float4*)(out + (size_t)ni * DFEAT))[c4] = make_float4(ax, ay, az, aw);
}

// ------------------------------------------------------------ GEMM1 + ReLU
// h[e,n,:] = relu(agg_x[n,:] @ W1[e] + b1[e]); grid (625, 4), 256 thr
__launch_bounds__(256)
__global__ void k_gemm1(const float* __restrict__ aggx, const float* __restrict__ W1,
                        const float* __restrict__ bias1, float* __restrict__ h) {
    __shared__ float As[32 * 128];  // 16 KB
    __shared__ float Bs[64 * 128];  // 32 KB (half of the K rows)
    int t = threadIdx.x;
    int e = blockIdx.y;
    int base = blockIdx.x * 32;
    int ng = t >> 5, cg = t & 31;

    float4* As4 = (float4*)As;
    float4* Bs4 = (float4*)Bs;
    const float4* srcA = (const float4*)aggx;
    const float4* Wb = (const float4*)(W1 + (size_t)e * DFEAT * DFEAT);

    for (int i = t; i < 1024; i += 256) {
        int row = i >> 5, c4 = i & 31;
        int n = base + row;
        As4[i] = (n < NNODES) ? srcA[(size_t)n * 32 + c4] : make_float4(0.f, 0.f, 0.f, 0.f);
    }

    float4 acc[4];
    for (int i = 0; i < 4; ++i) acc[i] = make_float4(0.f, 0.f, 0.f, 0.f);

    for (int half = 0; half < 2; ++half) {
        __syncthreads();  // As staged (iter0) / previous Bs reads done (iter1)
        for (int i = t; i < 2048; i += 256) Bs4[i] = Wb[half * 2048 + i];
        __syncthreads();
        int kbase = half * 16;  // float4 units along K
        for (int k4 = 0; k4 < 16; ++k4) {
            float4 b0 = Bs4[(4 * k4 + 0) * 32 + cg];
            float4 b1v = Bs4[(4 * k4 + 1) * 32 + cg];
            float4 b2v = Bs4[(4 * k4 + 2) * 32 + cg];
            float4 b3v = Bs4[(4 * k4 + 3) * 32 + cg];
#pragma unroll
            for (int i = 0; i < 4; ++i) {
                float4 a = As4[(ng * 4 + i) * 32 + (kbase + k4)];
                acc[i].x += a.x * b0.x + a.y * b1v.x + a.z * b2v.x + a.w * b3v.x;
                acc[i].y += a.x * b0.y + a.y * b1v.y + a.z * b2v.y + a.w * b3v.y;
                acc[i].z += a.x * b0.z + a.y * b1v.z + a.z * b2v.z + a.w * b3v.z;
                acc[i].w += a.x * b0.w + a.y * b1v.w + a.z * b2v.w + a.w * b3v.w;
            }
        }
    }

    float4 bv = ((const float4*)(bias1 + (size_t)e * DFEAT))[cg];
#pragma unroll
    for (int i = 0; i < 4; ++i) {
        int n = base + ng * 4 + i;
        if (n < NNODES) {
            float4 v;
            v.x = fmaxf(acc[i].x + bv.x, 0.f);
            v.y = fmaxf(acc[i].y + bv.y, 0.f);
            v.z = fmaxf(acc[i].z + bv.z, 0.f);
            v.w = fmaxf(acc[i].w + bv.w, 0.f);
            ((float4*)(h + ((size_t)e * NNODES + n) * DFEAT))[cg] = v;
        }
    }
}

// --------------------------------------- GEMM2 fused with gate-combine+bias
// out[n,:] = sum_e gates[n,e] * (agg_h[e,n,:] @ W2[e] + b2[e]); grid 625
__launch_bounds__(256)
__global__ void k_gemm2(const float* __restrict__ aggh, const float* __restrict__ W2,
                        const float* __restrict__ bias2, const float* __restrict__ gates,
                        float* __restrict__ out) {
    __shared__ float As[32 * 128];
    __shared__ float Bs[64 * 128];
    int t = threadIdx.x;
    int base = blockIdx.x * 32;
    int ng = t >> 5, cg = t & 31;

    float4* As4 = (float4*)As;
    float4* Bs4 = (float4*)Bs;

    float4 acc[4];
    for (int i = 0; i < 4; ++i) acc[i] = make_float4(0.f, 0.f, 0.f, 0.f);

    for (int e = 0; e < NEXP; ++e) {
        __syncthreads();  // previous expert's As/Bs reads done
        const float4* srcA = (const float4*)(aggh + (size_t)e * NNODES * DFEAT);
        for (int i = t; i < 1024; i += 256) {
            int row = i >> 5, c4 = i & 31;
            int n = base + row;
            As4[i] = (n < NNODES) ? srcA[(size_t)n * 32 + c4] : make_float4(0.f, 0.f, 0.f, 0.f);
        }
        const float4* Wb = (const float4*)(W2 + (size_t)e * DFEAT * DFEAT);

        float4 tmp[4];
        for (int i = 0; i < 4; ++i) tmp[i] = make_float4(0.f, 0.f, 0.f, 0.f);

        for (int half = 0; half < 2; ++half) {
            __syncthreads();  // As staged / previous Bs reads done
            for (int i = t; i < 2048; i += 256) Bs4[i] = Wb[half * 2048 + i];
            __syncthreads();
            int kbase = half * 16;
            for (int k4 = 0; k4 < 16; ++k4) {
                float4 b0 = Bs4[(4 * k4 + 0) * 32 + cg];
                float4 b1v = Bs4[(4 * k4 + 1) * 32 + cg];
                float4 b2v = Bs4[(4 * k4 + 2) * 32 + cg];
                float4 b3v = Bs4[(4 * k4 + 3) * 32 + cg];
#pragma unroll
                for (int i = 0; i < 4; ++i) {
                    float4 a = As4[(ng * 4 + i) * 32 + (kbase + k4)];
                    tmp[i].x += a.x * b0.x + a.y * b1v.x + a.z * b2v.x + a.w * b3v.x;
                    tmp[i].y += a.x * b0.y + a.y * b1v.y + a.z * b2v.y + a.w * b3v.y;
                    tmp[i].z += a.x * b0.z + a.y * b1v.z + a.z * b2v.z + a.w * b3v.z;
                    tmp[i].w += a.x * b0.w + a.y * b1v.w + a.z * b2v.w + a.w * b3v.w;
                }
            }
        }

        float4 bv = ((const float4*)(bias2 + (size_t)e * DFEAT))[cg];
#pragma unroll
        for (int i = 0; i < 4; ++i) {
            int n = base + ng * 4 + i;
            float g = (n < NNODES) ? gates[(size_t)n * 4 + e] : 0.f;
            acc[i].x += g * (tmp[i].x + bv.x);
            acc[i].y += g * (tmp[i].y + bv.y);
            acc[i].z += g * (tmp[i].z + bv.z);
            acc[i].w += g * (tmp[i].w + bv.w);
        }
    }

#pragma unroll
    for (int i = 0; i < 4; ++i) {
        int n = base + ng * 4 + i;
        if (n < NNODES) {
            ((float4*)(out + (size_t)n * DFEAT))[cg] = acc[i];
        }
    }
}

// ------------------------------------------------------------ load loss
__global__ void k_loss(const float* __restrict__ importance, float* __restrict__ out_loss) {
    if (threadIdx.x == 0 && blockIdx.x == 0) {
        float v0 = importance[0], v1 = importance[1], v2 = importance[2], v3 = importance[3];
        float mean = 0.25f * (v0 + v1 + v2 + v3);
        float d0 = v0 - mean, d1 = v1 - mean, d2 = v2 - mean, d3 = v3 - mean;
        float var = 0.25f * (d0 * d0 + d1 * d1 + d2 * d2 + d3 * d3);
        out_loss[0] = 0.01f * var / (mean * mean + 1e-10f);
    }
}

// --------------------------------------------------------------- launcher
extern "C" void kernel_launch(void* const* d_in, const int* in_sizes, int n_in,
                              void* d_out, int out_size, void* d_ws, size_t ws_size,
                              hipStream_t stream) {
    const float* x      = (const float*)d_in[0];
    const int*   ei     = (const int*)d_in[1];
    const float* x_agg  = (const float*)d_in[2];
    const float* w_gate = (const float*)d_in[3];
    const float* thr    = (const float*)d_in[4];
    const float* mask   = (const float*)d_in[5];
    const float* W1     = (const float*)d_in[6];
    const float* b1     = (const float*)d_in[7];
    const float* W2     = (const float*)d_in[8];
    const float* b2     = (const float*)d_in[9];
    float* out = (float*)d_out;
    float* ws  = (float*)d_ws;

    float* deg        = ws;
    int*   cursor     = (int*)(ws + 20000);
    float* importance = ws + 40000;
    int*   rowstart   = (int*)(ws + 40960);
    int*   csrc       = (int*)(ws + 61440);
    float* cnrm       = ws + 221440;
    float* gates      = ws + 381440;
    float* aggx       = ws + 461440;
    float* h          = ws + 3021440;
    float* aggh       = ws + 13261440;

    // zero deg / cursor / importance in one shot
    hipMemsetAsync(d_ws, 0, 40008 * sizeof(float), stream);

    k_deg<<<(NEDGES + 255) / 256, 256, 0, stream>>>(ei, deg);
    k_scan<<<1, 256, 0, stream>>>(deg, rowstart);
    k_fill<<<(NEDGES + 255) / 256, 256, 0, stream>>>(ei, deg, rowstart, cursor, csrc, cnrm);
    k_gate<<<(NNODES + 255) / 256, 256, 0, stream>>>(x_agg, w_gate, thr, mask, gates, importance);
    k_gatheragg<<<(NNODES * 32 + 255) / 256, 256, 0, stream>>>(x, rowstart, csrc, cnrm, aggx, 1);
    k_gemm1<<<dim3((NNODES + 31) / 32, NEXP), 256, 0, stream>>>(aggx, W1, b1, h);
    k_gatheragg<<<(NEXP * NNODES * 32 + 255) / 256, 256, 0, stream>>>(h, rowstart, csrc, cnrm, aggh, NEXP);
    k_gemm2<<<(NNODES + 31) / 32, 256, 0, stream>>>(aggh, W2, b2, gates, out);
    k_loss<<<1, 64, 0, stream>>>(importance, out + (size_t)NNODES * DFEAT);
}

// Round 3
// 277.817 us; speedup vs baseline: 1.6265x; 1.6265x over previous
//
#include <hip/hip_runtime.h>
#include <cstdint>
#include <cstddef>

#define NNODES 20000
#define NEDGES 160000
#define DFEAT  128
#define NEXP   4

typedef unsigned short u16;
typedef __attribute__((ext_vector_type(8))) short short8v;   // 8 bf16 (4 VGPRs)
typedef __attribute__((ext_vector_type(4))) float float4v;   // 4 f32 acc

static __device__ __forceinline__ u16 f2bf(float f) {
    union { float f; unsigned int i; } v; v.f = f;
    unsigned int r = (v.i + 0x7FFFu + ((v.i >> 16) & 1u)) >> 16;  // RNE
    return (u16)r;
}
static __device__ __forceinline__ float lo2f(unsigned int u) { return __uint_as_float(u << 16); }
static __device__ __forceinline__ float hi2f(unsigned int u) { return __uint_as_float(u & 0xFFFF0000u); }

// ---------------- workspace layout (float-element offsets; all 16B-aligned) --
// deg        0        [20000]  (zeroed)
// cursor     20000    [20000]  (zeroed)
// importance 40000    [8]      (zeroed)
// rowstart   40960    [20001] int
// csrc       61440    [160000] int
// cnrm       221440   [160000]
// gates      381440   [80000]
// W1t        461440   (65536 u16 = 32768 f)  bf16 [4][128c][128k]
// W2t        494208   (65536 u16)
// aggx       526976   (2.56M u16 = 1.28M f)  bf16 [20000][128]
// h          1806976  (10.24M u16 = 5.12M f) bf16 [4][20000][128]
// aggh       6926976  (10.24M u16)           bf16 [4][20000][128]
// end        12046976 floats = 48.2 MB

// ---------------------------------------------------------------- degree
__global__ void k_deg(const int* __restrict__ ei, float* __restrict__ deg) {
    int e = blockIdx.x * 256 + threadIdx.x;
    if (e < NEDGES) atomicAdd(&deg[ei[NEDGES + e]], 1.0f);
}

// ------------------------------------------------- exclusive scan (1 block)
__global__ void k_scan(const float* __restrict__ deg, int* __restrict__ rowstart) {
    __shared__ int part[256];
    int t = threadIdx.x;
    const int PER = (NNODES + 255) / 256;  // 79
    int base = t * PER;
    int s = 0;
    for (int i = 0; i < PER; ++i) {
        int n = base + i;
        if (n < NNODES) s += (int)deg[n];
    }
    part[t] = s;
    __syncthreads();
    for (int off = 1; off < 256; off <<= 1) {
        int v = (t >= off) ? part[t - off] : 0;
        __syncthreads();
        part[t] += v;
        __syncthreads();
    }
    int run = part[t] - s;
    for (int i = 0; i < PER; ++i) {
        int n = base + i;
        if (n < NNODES) {
            rowstart[n] = run;
            run += (int)deg[n];
        }
    }
    if (t == 255) rowstart[NNODES] = part[255];
}

// ------------------------------------------------------- CSR fill + norm
__global__ void k_fill(const int* __restrict__ ei, const float* __restrict__ deg,
                       const int* __restrict__ rowstart, int* __restrict__ cursor,
                       int* __restrict__ csrc, float* __restrict__ cnrm) {
    int e = blockIdx.x * 256 + threadIdx.x;
    if (e >= NEDGES) return;
    int s = ei[e], d = ei[NEDGES + e];
    int pos = atomicAdd(&cursor[d], 1);
    int slot = rowstart[d] + pos;
    csrc[slot] = s;
    float ds = fmaxf(deg[s], 1.0f), dd = fmaxf(deg[d], 1.0f);
    cnrm[slot] = 1.0f / sqrtf(ds * dd);
}

// --------------------------------------------- weight transpose + bf16 cast
// Wt[arr][e][c][k] = bf16(W[arr][e][k][c]); 131072 threads exactly
__global__ void k_prepw(const float* __restrict__ W1, const float* __restrict__ W2,
                        u16* __restrict__ W1t, u16* __restrict__ W2t) {
    int gid = blockIdx.x * 256 + threadIdx.x;
    int arr = gid >> 16;
    int rem = gid & 65535;            // e*16384 + c*128 + k
    int e = rem >> 14;
    int cw = rem & 16383;
    int c = cw >> 7, k = cw & 127;
    const float* W = arr ? W2 : W1;
    u16* Wt = arr ? W2t : W1t;
    Wt[rem] = f2bf(W[(size_t)e * 16384 + (size_t)k * 128 + c]);
}

// ------------------------------------------------------------- gating (f32)
__global__ void k_gate(const float* __restrict__ x_agg, const float* __restrict__ w_gate,
                       const float* __restrict__ thr, const float* __restrict__ mask,
                       float* __restrict__ gates, float* __restrict__ importance) {
    int n = blockIdx.x * 256 + threadIdx.x;
    float4 lg = make_float4(0.f, 0.f, 0.f, 0.f);
    if (n < NNODES) {
        const float4* xr = (const float4*)(x_agg + (size_t)n * DFEAT);
        const float4* wg = (const float4*)w_gate;  // one float4 (4 experts) per k-row
        for (int k4 = 0; k4 < 32; ++k4) {
            float4 xv = xr[k4];
            float4 w0 = wg[4 * k4 + 0], w1 = wg[4 * k4 + 1];
            float4 w2 = wg[4 * k4 + 2], w3 = wg[4 * k4 + 3];
            lg.x += xv.x * w0.x + xv.y * w1.x + xv.z * w2.x + xv.w * w3.x;
            lg.y += xv.x * w0.y + xv.y * w1.y + xv.z * w2.y + xv.w * w3.y;
            lg.z += xv.x * w0.z + xv.y * w1.z + xv.z * w2.z + xv.w * w3.z;
            lg.w += xv.x * w0.w + xv.y * w1.w + xv.z * w2.w + xv.w * w3.w;
        }
    }
    float g[4];
    float lv[4] = {lg.x, lg.y, lg.z, lg.w};
    for (int e = 0; e < 4; ++e) {
        float sgm = 1.0f / (1.0f + expf(-lv[e]));
        g[e] = (sgm - thr[e] > 0.0f) ? mask[e] : 0.0f;
        if (n >= NNODES) g[e] = 0.0f;
    }
    if (n < NNODES) ((float4*)gates)[n] = make_float4(g[0], g[1], g[2], g[3]);
    int lane = threadIdx.x & 63;
    for (int e = 0; e < 4; ++e) {
        float v = g[e];
        for (int off = 32; off >= 1; off >>= 1) v += __shfl_down(v, off);
        if (lane == 0) atomicAdd(&importance[e], v);
    }
}

// --------------------------------- agg_x = gather-sum of x (f32 in, bf16 out)
__global__ void k_aggx(const float* __restrict__ x, const int* __restrict__ rowstart,
                       const int* __restrict__ csrc, const float* __restrict__ cnrm,
                       u16* __restrict__ aggx) {
    int gid = blockIdx.x * 256 + threadIdx.x;
    if (gid >= NNODES * 32) return;
    int c4 = gid & 31, node = gid >> 5;
    int r0 = rowstart[node], r1 = rowstart[node + 1];
    float ax = 0.f, ay = 0.f, az = 0.f, aw = 0.f;
    for (int j = r0; j < r1; ++j) {
        int s = csrc[j];
        float wv = cnrm[j];
        float4 v = ((const float4*)(x + (size_t)s * DFEAT))[c4];
        ax += wv * v.x; ay += wv * v.y; az += wv * v.z; aw += wv * v.w;
    }
    uint2 o;
    o.x = ((unsigned)f2bf(ay) << 16) | f2bf(ax);
    o.y = ((unsigned)f2bf(aw) << 16) | f2bf(az);
    ((uint2*)(aggx + (size_t)node * DFEAT))[c4] = o;
}

// ----------------------------------- GEMM1: h[e] = relu(aggx @ W1[e] + b1[e])
// grid (250, 4experts) x 320 thr; wave = 16 rows x 128 cols; no LDS
__launch_bounds__(320)
__global__ void k_gemm1(const u16* __restrict__ aggx, const u16* __restrict__ W1t,
                        const float* __restrict__ b1, u16* __restrict__ h) {
    int e = blockIdx.y;
    int w = threadIdx.x >> 6, l = threadIdx.x & 63;
    int rbase = blockIdx.x * 80 + w * 16;
    int lr = l & 15, kg = l >> 4;

    const short8v* A8 = (const short8v*)aggx;
    const short8v* B8 = (const short8v*)(W1t + (size_t)e * 16384);

    short8v a[4];
#pragma unroll
    for (int kk = 0; kk < 4; ++kk) a[kk] = A8[(size_t)(rbase + lr) * 16 + kk * 4 + kg];

    u16* hb = h + (size_t)e * NNODES * DFEAT;
#pragma unroll
    for (int c = 0; c < 8; ++c) {
        float4v acc = {0.f, 0.f, 0.f, 0.f};
#pragma unroll
        for (int kk = 0; kk < 4; ++kk) {
            short8v b = B8[(c * 16 + lr) * 16 + kk * 4 + kg];
            acc = __builtin_amdgcn_mfma_f32_16x16x32_bf16(a[kk], b, acc, 0, 0, 0);
        }
        float bv = b1[e * DFEAT + c * 16 + lr];
#pragma unroll
        for (int i = 0; i < 4; ++i) {
            int node = rbase + kg * 4 + i;
            float vv = fmaxf(acc[i] + bv, 0.f);
            hb[(size_t)node * DFEAT + c * 16 + lr] = f2bf(vv);
        }
    }
}

// ------------------------------- agg_h = gather-sum of h (bf16 in, bf16 out)
__global__ void k_aggh(const u16* __restrict__ h, const int* __restrict__ rowstart,
                       const int* __restrict__ csrc, const float* __restrict__ cnrm,
                       u16* __restrict__ aggh) {
    int gid = blockIdx.x * 256 + threadIdx.x;
    if (gid >= NEXP * NNODES * 16) return;
    int l8 = gid & 15;
    int ni = gid >> 4;
    int node = ni % NNODES;
    int e = ni / NNODES;
    const u16* hb = h + (size_t)e * NNODES * DFEAT;
    int r0 = rowstart[node], r1 = rowstart[node + 1];
    float a0 = 0.f, a1 = 0.f, a2 = 0.f, a3 = 0.f, a4 = 0.f, a5 = 0.f, a6 = 0.f, a7 = 0.f;
    for (int j = r0; j < r1; ++j) {
        int s = csrc[j];
        float wv = cnrm[j];
        uint4 v = ((const uint4*)(hb + (size_t)s * DFEAT))[l8];
        a0 += wv * lo2f(v.x); a1 += wv * hi2f(v.x);
        a2 += wv * lo2f(v.y); a3 += wv * hi2f(v.y);
        a4 += wv * lo2f(v.z); a5 += wv * hi2f(v.z);
        a6 += wv * lo2f(v.w); a7 += wv * hi2f(v.w);
    }
    uint4 o;
    o.x = ((unsigned)f2bf(a1) << 16) | f2bf(a0);
    o.y = ((unsigned)f2bf(a3) << 16) | f2bf(a2);
    o.z = ((unsigned)f2bf(a5) << 16) | f2bf(a4);
    o.w = ((unsigned)f2bf(a7) << 16) | f2bf(a6);
    ((uint4*)(aggh + (size_t)ni * DFEAT))[l8] = o;
}

// ------------- GEMM2 fused gate-combine: out = sum_e g[n,e]*(aggh[e]@W2[e]+b2[e])
// grid (250, 4 col-splits) x 320 thr; wave = 16 rows x 32 cols; no LDS
__launch_bounds__(320)
__global__ void k_gemm2(const u16* __restrict__ aggh, const u16* __restrict__ W2t,
                        const float* __restrict__ b2, const float* __restrict__ gates,
                        float* __restrict__ out) {
    int w = threadIdx.x >> 6, l = threadIdx.x & 63;
    int rbase = blockIdx.x * 80 + w * 16;
    int cb = blockIdx.y * 2;  // c-frag base (2 frags = 32 cols per block)
    int lr = l & 15, kg = l >> 4;

    float4v acc[2];
    acc[0] = (float4v){0.f, 0.f, 0.f, 0.f};
    acc[1] = (float4v){0.f, 0.f, 0.f, 0.f};

#pragma unroll
    for (int e = 0; e < NEXP; ++e) {
        const short8v* A8 = (const short8v*)(aggh + (size_t)e * NNODES * DFEAT);
        const short8v* B8 = (const short8v*)(W2t + (size_t)e * 16384);
        short8v a[4];
#pragma unroll
        for (int kk = 0; kk < 4; ++kk) a[kk] = A8[(size_t)(rbase + lr) * 16 + kk * 4 + kg];
        float g[4];
#pragma unroll
        for (int i = 0; i < 4; ++i) g[i] = gates[(size_t)(rbase + kg * 4 + i) * 4 + e];
#pragma unroll
        for (int c = 0; c < 2; ++c) {
            float4v t = {0.f, 0.f, 0.f, 0.f};
#pragma unroll
            for (int kk = 0; kk < 4; ++kk) {
                short8v b = B8[((cb + c) * 16 + lr) * 16 + kk * 4 + kg];
                t = __builtin_amdgcn_mfma_f32_16x16x32_bf16(a[kk], b, t, 0, 0, 0);
            }
            float bv = b2[e * DFEAT + (cb + c) * 16 + lr];
#pragma unroll
            for (int i = 0; i < 4; ++i) acc[c][i] += g[i] * (t[i] + bv);
        }
    }

#pragma unroll
    for (int c = 0; c < 2; ++c)
#pragma unroll
        for (int i = 0; i < 4; ++i) {
            int node = rbase + kg * 4 + i;
            out[(size_t)node * DFEAT + (cb + c) * 16 + lr] = acc[c][i];
        }
}

// ------------------------------------------------------------ load loss
__global__ void k_loss(const float* __restrict__ importance, float* __restrict__ out_loss) {
    if (threadIdx.x == 0 && blockIdx.x == 0) {
        float v0 = importance[0], v1 = importance[1], v2 = importance[2], v3 = importance[3];
        float mean = 0.25f * (v0 + v1 + v2 + v3);
        float d0 = v0 - mean, d1 = v1 - mean, d2 = v2 - mean, d3 = v3 - mean;
        float var = 0.25f * (d0 * d0 + d1 * d1 + d2 * d2 + d3 * d3);
        out_loss[0] = 0.01f * var / (mean * mean + 1e-10f);
    }
}

// --------------------------------------------------------------- launcher
extern "C" void kernel_launch(void* const* d_in, const int* in_sizes, int n_in,
                              void* d_out, int out_size, void* d_ws, size_t ws_size,
                              hipStream_t stream) {
    const float* x      = (const float*)d_in[0];
    const int*   ei     = (const int*)d_in[1];
    const float* x_agg  = (const float*)d_in[2];
    const float* w_gate = (const float*)d_in[3];
    const float* thr    = (const float*)d_in[4];
    const float* mask   = (const float*)d_in[5];
    const float* W1     = (const float*)d_in[6];
    const float* b1     = (const float*)d_in[7];
    const float* W2     = (const float*)d_in[8];
    const float* b2     = (const float*)d_in[9];
    float* out = (float*)d_out;
    float* ws  = (float*)d_ws;

    float* deg        = ws;
    int*   cursor     = (int*)(ws + 20000);
    float* importance = ws + 40000;
    int*   rowstart   = (int*)(ws + 40960);
    int*   csrc       = (int*)(ws + 61440);
    float* cnrm       = ws + 221440;
    float* gates      = ws + 381440;
    u16*   W1t        = (u16*)(ws + 461440);
    u16*   W2t        = (u16*)(ws + 494208);
    u16*   aggx       = (u16*)(ws + 526976);
    u16*   h          = (u16*)(ws + 1806976);
    u16*   aggh       = (u16*)(ws + 6926976);

    hipMemsetAsync(d_ws, 0, 40008 * sizeof(float), stream);

    k_deg<<<(NEDGES + 255) / 256, 256, 0, stream>>>(ei, deg);
    k_scan<<<1, 256, 0, stream>>>(deg, rowstart);
    k_fill<<<(NEDGES + 255) / 256, 256, 0, stream>>>(ei, deg, rowstart, cursor, csrc, cnrm);
    k_prepw<<<512, 256, 0, stream>>>(W1, W2, W1t, W2t);
    k_gate<<<(NNODES + 255) / 256, 256, 0, stream>>>(x_agg, w_gate, thr, mask, gates, importance);
    k_aggx<<<(NNODES * 32) / 256, 256, 0, stream>>>(x, rowstart, csrc, cnrm, aggx);
    k_gemm1<<<dim3(250, NEXP), 320, 0, stream>>>(aggx, W1t, b1, h);
    k_aggh<<<(NEXP * NNODES * 16) / 256, 256, 0, stream>>>(h, rowstart, csrc, cnrm, aggh);
    k_gemm2<<<dim3(250, 4), 320, 0, stream>>>(aggh, W2t, b2, gates, out);
    k_loss<<<1, 64, 0, stream>>>(importance, out + (size_t)NNODES * DFEAT);
}

// Round 5
// 258.804 us; speedup vs baseline: 1.7460x; 1.0735x over previous
//
#include <hip/hip_runtime.h>
#include <cstdint>
#include <cstddef>

#define NNODES 20000
#define NEDGES 160000
#define DFEAT  128
#define NEXP   4

typedef unsigned short u16;
typedef __attribute__((ext_vector_type(8))) short short8v;   // 8 bf16 (4 VGPRs)
typedef __attribute__((ext_vector_type(4))) float float4v;   // 4 f32 acc

static __device__ __forceinline__ u16 f2bf(float f) {
    union { float f; unsigned int i; } v; v.f = f;
    unsigned int r = (v.i + 0x7FFFu + ((v.i >> 16) & 1u)) >> 16;  // RNE
    return (u16)r;
}
static __device__ __forceinline__ float lo2f(unsigned int u) { return __uint_as_float(u << 16); }
static __device__ __forceinline__ float hi2f(unsigned int u) { return __uint_as_float(u & 0xFFFF0000u); }

// ---------------- workspace layout (float-element offsets; all 16B-aligned) --
// deg        0        [20000]  (zeroed)
// cursor     20000    [20000]  (zeroed)
// importance 40000    [8]      (zeroed)
// rowstart   40960    [20001] int
// csrc       61440    [160000] int
// cnrm       221440   [160000]
// gates      381440   [80000]
// W1t        461440   (65536 u16)  bf16 [4][128c][128k]
// W2t        494208   (65536 u16)
// aggx       526976   (2.56M u16)  bf16 [20000][128]
// h          1806976  (10.24M u16) bf16 [4][20000][128]
// aggh       6926976  (10.24M u16) bf16 [4][20000][128]

// ---------------------- fused independent pre-work: deg | prepw | gate -------
// blocks [0,625): degree atomics; [625,1137): weight transpose; [1137,1216): gate
__global__ void k_pre(const int* __restrict__ ei,
                      const float* __restrict__ W1, const float* __restrict__ W2,
                      const float* __restrict__ x_agg, const float* __restrict__ w_gate,
                      const float* __restrict__ thr, const float* __restrict__ mask,
                      float* __restrict__ deg, u16* __restrict__ W1t, u16* __restrict__ W2t,
                      float* __restrict__ gates, float* __restrict__ importance) {
    int b = blockIdx.x;
    if (b < 625) {                       // ---- degree histogram
        int e = b * 256 + threadIdx.x;
        if (e < NEDGES) atomicAdd(&deg[ei[NEDGES + e]], 1.0f);
        return;
    }
    if (b < 1137) {                      // ---- weight transpose + bf16
        int gid = (b - 625) * 256 + threadIdx.x;   // [0, 131072)
        int arr = gid >> 16;
        int rem = gid & 65535;           // e*16384 + c*128 + k
        int e = rem >> 14;
        int cw = rem & 16383;
        int c = cw >> 7, k = cw & 127;
        const float* W = arr ? W2 : W1;
        u16* Wt = arr ? W2t : W1t;
        Wt[rem] = f2bf(W[(size_t)e * 16384 + (size_t)k * 128 + c]);
        return;
    }
    // ---- gating (f32 exact)
    int n = (b - 1137) * 256 + threadIdx.x;
    float4 lg = make_float4(0.f, 0.f, 0.f, 0.f);
    if (n < NNODES) {
        const float4* xr = (const float4*)(x_agg + (size_t)n * DFEAT);
        const float4* wg = (const float4*)w_gate;
        for (int k4 = 0; k4 < 32; ++k4) {
            float4 xv = xr[k4];
            float4 w0 = wg[4 * k4 + 0], w1 = wg[4 * k4 + 1];
            float4 w2 = wg[4 * k4 + 2], w3 = wg[4 * k4 + 3];
            lg.x += xv.x * w0.x + xv.y * w1.x + xv.z * w2.x + xv.w * w3.x;
            lg.y += xv.x * w0.y + xv.y * w1.y + xv.z * w2.y + xv.w * w3.y;
            lg.z += xv.x * w0.z + xv.y * w1.z + xv.z * w2.z + xv.w * w3.z;
            lg.w += xv.x * w0.w + xv.y * w1.w + xv.z * w2.w + xv.w * w3.w;
        }
    }
    float g[4];
    float lv[4] = {lg.x, lg.y, lg.z, lg.w};
    for (int e = 0; e < 4; ++e) {
        float sgm = 1.0f / (1.0f + expf(-lv[e]));
        g[e] = (sgm - thr[e] > 0.0f) ? mask[e] : 0.0f;
        if (n >= NNODES) g[e] = 0.0f;
    }
    if (n < NNODES) ((float4*)gates)[n] = make_float4(g[0], g[1], g[2], g[3]);
    int lane = threadIdx.x & 63;
    for (int e = 0; e < 4; ++e) {
        float v = g[e];
        for (int off = 32; off >= 1; off >>= 1) v += __shfl_down(v, off);
        if (lane == 0) atomicAdd(&importance[e], v);
    }
}

// ------------------------------------------------- exclusive scan (1 block)
__global__ void k_scan(const float* __restrict__ deg, int* __restrict__ rowstart) {
    __shared__ int part[1024];
    int t = threadIdx.x;
    const int PER = 20;                 // 1024*20 >= 20000
    int base = t * PER;
    int s = 0;
    for (int i = 0; i < PER; ++i) {
        int n = base + i;
        if (n < NNODES) s += (int)deg[n];
    }
    part[t] = s;
    __syncthreads();
    for (int off = 1; off < 1024; off <<= 1) {
        int v = (t >= off) ? part[t - off] : 0;
        __syncthreads();
        part[t] += v;
        __syncthreads();
    }
    int run = part[t] - s;
    for (int i = 0; i < PER; ++i) {
        int n = base + i;
        if (n < NNODES) {
            rowstart[n] = run;
            run += (int)deg[n];
        }
    }
    if (t == 1023) rowstart[NNODES] = part[1023];
}

// ------------------------------------------------------- CSR fill + norm
__global__ void k_fill(const int* __restrict__ ei, const float* __restrict__ deg,
                       const int* __restrict__ rowstart, int* __restrict__ cursor,
                       int* __restrict__ csrc, float* __restrict__ cnrm) {
    int e = blockIdx.x * 256 + threadIdx.x;
    if (e >= NEDGES) return;
    int s = ei[e], d = ei[NEDGES + e];
    int pos = atomicAdd(&cursor[d], 1);
    int slot = rowstart[d] + pos;
    csrc[slot] = s;
    float ds = fmaxf(deg[s], 1.0f), dd = fmaxf(deg[d], 1.0f);
    cnrm[slot] = 1.0f / sqrtf(ds * dd);
}

// --------------------------------- agg_x = gather-sum of x (f32 in, bf16 out)
__global__ void k_aggx(const float* __restrict__ x, const int* __restrict__ rowstart,
                       const int* __restrict__ csrc, const float* __restrict__ cnrm,
                       u16* __restrict__ aggx) {
    int gid = blockIdx.x * 256 + threadIdx.x;
    if (gid >= NNODES * 32) return;
    int c4 = gid & 31, node = gid >> 5;
    int r0 = rowstart[node], r1 = rowstart[node + 1];
    float ax = 0.f, ay = 0.f, az = 0.f, aw = 0.f;
    for (int j = r0; j < r1; ++j) {
        int s = csrc[j];
        float wv = cnrm[j];
        float4 v = ((const float4*)(x + (size_t)s * DFEAT))[c4];
        ax += wv * v.x; ay += wv * v.y; az += wv * v.z; aw += wv * v.w;
    }
    uint2 o;
    o.x = ((unsigned)f2bf(ay) << 16) | f2bf(ax);
    o.y = ((unsigned)f2bf(aw) << 16) | f2bf(az);
    ((uint2*)(aggx + (size_t)node * DFEAT))[c4] = o;
}

// ----------------------------------- GEMM1: h[e] = relu(aggx @ W1[e] + b1[e])
__launch_bounds__(320)
__global__ void k_gemm1(const u16* __restrict__ aggx, const u16* __restrict__ W1t,
                        const float* __restrict__ b1, u16* __restrict__ h) {
    int e = blockIdx.y;
    int w = threadIdx.x >> 6, l = threadIdx.x & 63;
    int rbase = blockIdx.x * 80 + w * 16;
    int lr = l & 15, kg = l >> 4;

    const short8v* A8 = (const short8v*)aggx;
    const short8v* B8 = (const short8v*)(W1t + (size_t)e * 16384);

    short8v a[4];
#pragma unroll
    for (int kk = 0; kk < 4; ++kk) a[kk] = A8[(size_t)(rbase + lr) * 16 + kk * 4 + kg];

    u16* hb = h + (size_t)e * NNODES * DFEAT;
#pragma unroll
    for (int c = 0; c < 8; ++c) {
        float4v acc = {0.f, 0.f, 0.f, 0.f};
#pragma unroll
        for (int kk = 0; kk < 4; ++kk) {
            short8v b = B8[(c * 16 + lr) * 16 + kk * 4 + kg];
            acc = __builtin_amdgcn_mfma_f32_16x16x32_bf16(a[kk], b, acc, 0, 0, 0);
        }
        float bv = b1[e * DFEAT + c * 16 + lr];
#pragma unroll
        for (int i = 0; i < 4; ++i) {
            int node = rbase + kg * 4 + i;
            float vv = fmaxf(acc[i] + bv, 0.f);
            hb[(size_t)node * DFEAT + c * 16 + lr] = f2bf(vv);
        }
    }
}

// ------------- agg_h gather (bf16 in/out), SKIPPING gated-off (e,node) pairs
__global__ void k_aggh(const u16* __restrict__ h, const int* __restrict__ rowstart,
                       const int* __restrict__ csrc, const float* __restrict__ cnrm,
                       const float* __restrict__ gates, u16* __restrict__ aggh) {
    int gid = blockIdx.x * 256 + threadIdx.x;
    if (gid >= NEXP * NNODES * 16) return;
    int l8 = gid & 15;
    int ni = gid >> 4;
    int node = ni % NNODES;
    int e = ni / NNODES;
    if (gates[(size_t)node * 4 + e] == 0.0f) return;  // contribution multiplied by 0 later
    const u16* hb = h + (size_t)e * NNODES * DFEAT;
    int r0 = rowstart[node], r1 = rowstart[node + 1];
    float a0 = 0.f, a1 = 0.f, a2 = 0.f, a3 = 0.f, a4 = 0.f, a5 = 0.f, a6 = 0.f, a7 = 0.f;
    for (int j = r0; j < r1; ++j) {
        int s = csrc[j];
        float wv = cnrm[j];
        uint4 v = ((const uint4*)(hb + (size_t)s * DFEAT))[l8];
        a0 += wv * lo2f(v.x); a1 += wv * hi2f(v.x);
        a2 += wv * lo2f(v.y); a3 += wv * hi2f(v.y);
        a4 += wv * lo2f(v.z); a5 += wv * hi2f(v.z);
        a6 += wv * lo2f(v.w); a7 += wv * hi2f(v.w);
    }
    uint4 o;
    o.x = ((unsigned)f2bf(a1) << 16) | f2bf(a0);
    o.y = ((unsigned)f2bf(a3) << 16) | f2bf(a2);
    o.z = ((unsigned)f2bf(a5) << 16) | f2bf(a4);
    o.w = ((unsigned)f2bf(a7) << 16) | f2bf(a6);
    ((uint4*)(aggh + (size_t)ni * DFEAT))[l8] = o;
}

// ------------- GEMM2 fused gate-combine (+ load-loss in thread (0,0))
__launch_bounds__(320)
__global__ void k_gemm2(const u16* __restrict__ aggh, const u16* __restrict__ W2t,
                        const float* __restrict__ b2, const float* __restrict__ gates,
                        const float* __restrict__ importance, float* __restrict__ out) {
    if (blockIdx.x == 0 && blockIdx.y == 0 && threadIdx.x == 0) {
        float v0 = importance[0], v1 = importance[1], v2 = importance[2], v3 = importance[3];
        float mean = 0.25f * (v0 + v1 + v2 + v3);
        float d0 = v0 - mean, d1 = v1 - mean, d2 = v2 - mean, d3 = v3 - mean;
        float var = 0.25f * (d0 * d0 + d1 * d1 + d2 * d2 + d3 * d3);
        out[(size_t)NNODES * DFEAT] = 0.01f * var / (mean * mean + 1e-10f);
    }
    int w = threadIdx.x >> 6, l = threadIdx.x & 63;
    int rbase = blockIdx.x * 80 + w * 16;
    int cb = blockIdx.y * 2;
    int lr = l & 15, kg = l >> 4;

    float4v acc[2];
    acc[0] = (float4v){0.f, 0.f, 0.f, 0.f};
    acc[1] = (float4v){0.f, 0.f, 0.f, 0.f};

#pragma unroll
    for (int e = 0; e < NEXP; ++e) {
        const short8v* A8 = (const short8v*)(aggh + (size_t)e * NNODES * DFEAT);
        const short8v* B8 = (const short8v*)(W2t + (size_t)e * 16384);
        short8v a[4];
#pragma unroll
        for (int kk = 0; kk < 4; ++kk) a[kk] = A8[(size_t)(rbase + lr) * 16 + kk * 4 + kg];
        float g[4];
#pragma unroll
        for (int i = 0; i < 4; ++i) g[i] = gates[(size_t)(rbase + kg * 4 + i) * 4 + e];
#pragma unroll
        for (int c = 0; c < 2; ++c) {
            float4v t = {0.f, 0.f, 0.f, 0.f};
#pragma unroll
            for (int kk = 0; kk < 4; ++kk) {
                short8v b = B8[((cb + c) * 16 + lr) * 16 + kk * 4 + kg];
                t = __builtin_amdgcn_mfma_f32_16x16x32_bf16(a[kk], b, t, 0, 0, 0);
            }
            float bv = b2[e * DFEAT + (cb + c) * 16 + lr];
#pragma unroll
            for (int i = 0; i < 4; ++i) acc[c][i] += g[i] * (t[i] + bv);
        }
    }

#pragma unroll
    for (int c = 0; c < 2; ++c)
#pragma unroll
        for (int i = 0; i < 4; ++i) {
            int node = rbase + kg * 4 + i;
            out[(size_t)node * DFEAT + (cb + c) * 16 + lr] = acc[c][i];
        }
}

// --------------------------------------------------------------- launcher
extern "C" void kernel_launch(void* const* d_in, const int* in_sizes, int n_in,
                              void* d_out, int out_size, void* d_ws, size_t ws_size,
                              hipStream_t stream) {
    const float* x      = (const float*)d_in[0];
    const int*   ei     = (const int*)d_in[1];
    const float* x_agg  = (const float*)d_in[2];
    const float* w_gate = (const float*)d_in[3];
    const float* thr    = (const float*)d_in[4];
    const float* mask   = (const float*)d_in[5];
    const float* W1     = (const float*)d_in[6];
    const float* b1     = (const float*)d_in[7];
    const float* W2     = (const float*)d_in[8];
    const float* b2     = (const float*)d_in[9];
    float* out = (float*)d_out;
    float* ws  = (float*)d_ws;

    float* deg        = ws;
    int*   cursor     = (int*)(ws + 20000);
    float* importance = ws + 40000;
    int*   rowstart   = (int*)(ws + 40960);
    int*   csrc       = (int*)(ws + 61440);
    float* cnrm       = ws + 221440;
    float* gates      = ws + 381440;
    u16*   W1t        = (u16*)(ws + 461440);
    u16*   W2t        = (u16*)(ws + 494208);
    u16*   aggx       = (u16*)(ws + 526976);
    u16*   h          = (u16*)(ws + 1806976);
    u16*   aggh       = (u16*)(ws + 6926976);

    hipMemsetAsync(d_ws, 0, 40008 * sizeof(float), stream);

    k_pre<<<1216, 256, 0, stream>>>(ei, W1, W2, x_agg, w_gate, thr, mask,
                                    deg, W1t, W2t, gates, importance);
    k_scan<<<1, 1024, 0, stream>>>(deg, rowstart);
    k_fill<<<(NEDGES + 255) / 256, 256, 0, stream>>>(ei, deg, rowstart, cursor, csrc, cnrm);
    k_aggx<<<(NNODES * 32) / 256, 256, 0, stream>>>(x, rowstart, csrc, cnrm, aggx);
    k_gemm1<<<dim3(250, NEXP), 320, 0, stream>>>(aggx, W1t, b1, h);
    k_aggh<<<(NEXP * NNODES * 16) / 256, 256, 0, stream>>>(h, rowstart, csrc, cnrm, gates, aggh);
    k_gemm2<<<dim3(250, 4), 320, 0, stream>>>(aggh, W2t, b2, gates, importance, out);
}